// Round 16
// baseline (32.115 us; speedup 1.0000x reference)
//
#include <hip/hip_runtime.h>

namespace {
constexpr int B = 4, C = 64, H = 128, W = 128, O = 64, KK = 9;
constexpr int PREPT = 256;
constexpr int MAINT = 256;                                      // 4 waves/block
constexpr int WF_ELEMS = KK * 4096;                             // 36864
constexpr size_t XT_BYTES = (size_t)B * H * W * C * 2;          // 16,777,216 (f16)
constexpr size_t WF_BYTES = (size_t)WF_ELEMS * 2;               // 73,728 (8KB per tap)
constexpr size_t WS_NEED  = XT_BYTES + WF_BYTES;
}

typedef float    f32x16 __attribute__((ext_vector_type(16)));
typedef _Float16 f16x2  __attribute__((ext_vector_type(2)));
typedef _Float16 f16x8  __attribute__((ext_vector_type(8)));

__device__ __forceinline__ unsigned hpack2(float a, float b) {  // 2x f32 -> packed f16
  f16x2 v; v[0] = (_Float16)a; v[1] = (_Float16)b;
  return __builtin_bit_cast(unsigned, v);
}
__device__ __forceinline__ void gload16(const void* g, void* l) {
  __builtin_amdgcn_global_load_lds(
      (const __attribute__((address_space(1))) unsigned*)g,
      (__attribute__((address_space(3))) unsigned*)l, 16, 0, 0);
}

// ---------- prep: x -> x_t[b][h][w][c] f16,  + weight -> 32x32x16 A-frag order ----------
// wf index: ((((tap*4 + ks)*2 + mt)*64 + lane)*8 + e)
//   o = mt*32 + (lane&31), c = ks*16 + (lane>>5)*8 + e   [A: row=lane&31, k=(lane>>5)*8+e]
__global__ __launch_bounds__(PREPT)
void prep_fused(const float* __restrict__ x, const float* __restrict__ wgt,
                unsigned* __restrict__ xt_u32, unsigned short* __restrict__ wf) {
  __shared__ float st[64][65];
  const int t = threadIdx.x;

  const int gid = blockIdx.x * PREPT + t;
  if (gid < WF_ELEMS) {
    const int e = gid & 7, lane = (gid >> 3) & 63;
    const int mt = (gid >> 9) & 1, ks = (gid >> 10) & 3, tap = gid >> 12;
    const int o = mt * 32 + (lane & 31);
    const int c = ks * 16 + ((lane >> 5) << 3) + e;
    const _Float16 hv = (_Float16)wgt[(size_t)o * (C * KK) + c * KK + tap];
    wf[gid] = __builtin_bit_cast(unsigned short, hv);
  }

  const int half = blockIdx.x & 1, h = (blockIdx.x >> 1) & 127, b = blockIdx.x >> 8;
  const int w0 = half * 64;
#pragma unroll
  for (int it = 0; it < 4; ++it) {
    const int w4 = (t & 15) * 4, c = it * 16 + (t >> 4);
    const float4 v = *(const float4*)&x[((size_t)(b * C + c) * H + h) * W + w0 + w4];
    st[w4 + 0][c] = v.x; st[w4 + 1][c] = v.y;
    st[w4 + 2][c] = v.z; st[w4 + 3][c] = v.w;
  }
  __syncthreads();
#pragma unroll
  for (int it = 0; it < 8; ++it) {
    const int idx = it * PREPT + t;
    const int w = idx >> 5, c2 = (idx & 31) * 2;
    xt_u32[(size_t)(((b * H + h) * W) + w0 + w) * 32 + (c2 >> 1)] = hpack2(st[w][c2], st[w][c2 + 1]);
  }
}

// ---------- main: 32x32x16 MFMA, 32 px/wave, 4-wave blocks, ring-4 gather ----------
__global__ __launch_bounds__(MAINT) __attribute__((amdgpu_waves_per_eu(3)))
void deform_mfma(const float* __restrict__ offs, const char* __restrict__ xt,
                 const char* __restrict__ wfg, float* __restrict__ out) {
  __shared__ unsigned short s_wf[2][4096];     // 16 KB: dbuf of one tap's A-fragments
  __shared__ unsigned short s_m[128 * 64];     // 16 KB: [block px][c] f16, swizzled
  __shared__ unsigned s_pw[4][KK][32][2];      // 9 KB:  f16x2 pairs (w00,w01),(w10,w11)
  __shared__ unsigned s_pp[4][KK][32];         // 4.5 KB: packed jc0|ic0<<7|jc1<<14|ic1<<21

  const int t = threadIdx.x, l = t & 63, wid = t >> 6;           // wid 0..3
  const int nid = (blockIdx.x & 7) * 64 + (blockIdx.x >> 3);     // bijective XCD swizzle (512)
  const int h = nid & 127, b = nid >> 7;
  const int wbase = wid * 32;                   // wave's first pixel (global w)

  // --- sampling params: wave's 32 px x 9 taps ---
#pragma unroll
  for (int it = 0; it < 5; ++it) {
    const int item = it * 64 + l;
    if (item < KK * 32) {
      const int tap = item >> 5, pix = item & 31;
      const int ki = tap / 3, kj = tap - ki * 3;
      const int w = wbase + pix;
      const float* ob = offs + ((size_t)b * (2 * KK) + 2 * tap) * (H * W) + h * W + w;
      const float oi = ob[0], oj = ob[H * W];
      const float ci = oi + (float)(h + ki - 1);
      const float cj = oj + (float)(w + kj - 1);
      const float fli = floorf(ci), flj = floorf(cj);
      const int i0 = (int)fli, j0 = (int)flj, i1 = i0 + 1, j1 = j0 + 1;
      const float fi = ci - fli, fj = cj - flj, gi = 1.f - fi, gj = 1.f - fj;
      const bool bi0 = (unsigned)i0 < (unsigned)H, bi1 = (unsigned)i1 < (unsigned)H;
      const bool bj0 = (unsigned)j0 < (unsigned)W, bj1 = (unsigned)j1 < (unsigned)W;
      const int ic0 = min(max(i0, 0), H - 1), ic1 = min(max(i1, 0), H - 1);
      const int jc0 = min(max(j0, 0), W - 1), jc1 = min(max(j1, 0), W - 1);
      const float w00 = gi * gj * (float)(bi0 && bj0);
      const float w01 = gi * fj * (float)(bi0 && bj1);
      const float w10 = fi * gj * (float)(bi1 && bj0);
      const float w11 = fi * fj * (float)(bi1 && bj1);
      s_pw[wid][tap][pix][0] = hpack2(w00, w01);
      s_pw[wid][tap][pix][1] = hpack2(w10, w11);
      s_pp[wid][tap][pix] = (unsigned)jc0 | ((unsigned)ic0 << 7) |
                            ((unsigned)jc1 << 14) | ((unsigned)ic1 << 21);
    }
  }

  // gather lane map: 8 lanes (oct) cover one pixel-corner's 128B contiguously
  const int pix8 = l >> 3, oct = l & 7, cb = oct << 4;
  const char* xb = xt + ((size_t)b * H * W << 7) + cb;   // per-image base + lane chunk

  char* smb = (char*)s_m;
  char* smw = (char*)s_wf;
  const int wb0 = ((wid * 32 + pix8) << 7) + ((oct ^ pix8) << 4);  // + HS*1024
  const int rdb = (wid * 32 + (l & 31)) << 7;                      // B-frag row base

  f32x16 acc[2];
  acc[0] = (f32x16)0.f;
  acc[1] = (f32x16)0.f;

  uint4 g[4][4];   // ring-4: stage HS covers px HS*8..HS*8+7, 4 corners (64 VGPR)
#define ISSUE(TAPX, HS) do {                                                   \
    const unsigned v_ = s_pp[wid][(TAPX)][(HS) * 8 + pix8];                    \
    const unsigned i0s = v_ & 0x3F80u;                                         \
    const unsigned j0_ = v_ & 0x7Fu;                                           \
    const unsigned j1_ = (v_ >> 14) & 0x7Fu;                                   \
    const unsigned i1s = (v_ >> 14) & 0x3F80u;                                 \
    g[HS][0] = *(const uint4*)(xb + ((size_t)(i0s | j0_) << 7));               \
    g[HS][1] = *(const uint4*)(xb + ((size_t)(i0s | j1_) << 7));               \
    g[HS][2] = *(const uint4*)(xb + ((size_t)(i1s | j0_) << 7));               \
    g[HS][3] = *(const uint4*)(xb + ((size_t)(i1s | j1_) << 7));               \
  } while (0)

#define LERPH(c0_, c1_, c2_, c3_) __builtin_bit_cast(unsigned, (f16x2)(        \
    __builtin_bit_cast(f16x2, c0_) * W00 + __builtin_bit_cast(f16x2, c1_) * W01 + \
    __builtin_bit_cast(f16x2, c2_) * W10 + __builtin_bit_cast(f16x2, c3_) * W11))

#define STAGE(TAPV, HS) do {                                                   \
    const uint2 pk = *(const uint2*)&s_pw[wid][(TAPV)][(HS) * 8 + pix8][0];    \
    const f16x2 pa_ = __builtin_bit_cast(f16x2, pk.x);                         \
    const f16x2 pb_ = __builtin_bit_cast(f16x2, pk.y);                         \
    const f16x2 W00 = {pa_[0], pa_[0]}, W01 = {pa_[1], pa_[1]};                \
    const f16x2 W10 = {pb_[0], pb_[0]}, W11 = {pb_[1], pb_[1]};                \
    uint4* gc = g[HS];                                                         \
    uint4 r;                                                                   \
    r.x = LERPH(gc[0].x, gc[1].x, gc[2].x, gc[3].x);                           \
    r.y = LERPH(gc[0].y, gc[1].y, gc[2].y, gc[3].y);                           \
    r.z = LERPH(gc[0].z, gc[1].z, gc[2].z, gc[3].z);                           \
    r.w = LERPH(gc[0].w, gc[1].w, gc[2].w, gc[3].w);                           \
    *(uint4*)(smb + wb0 + (HS) * 1024) = r;                                    \
  } while (0)

  // prologue: stage tap 0's weights (256 thr x 16B x 2 = 8KB); tap-0 gathers (full tap)
  gload16(wfg + (size_t)t * 16, smw + t * 16);
  gload16(wfg + 4096 + (size_t)t * 16, smw + 4096 + t * 16);
  ISSUE(0, 0); ISSUE(0, 1); ISSUE(0, 2); ISSUE(0, 3);

#pragma unroll 1
  for (int tap = 0; tap < KK; ++tap) {
    __syncthreads();   // wf buf[tap&1] ready; prev-buf reads done

    if (tap + 1 < KK) {            // stage next tap's weights into the other buffer
      const char* src = wfg + (size_t)(tap + 1) * 8192 + t * 16;
      char* dst = smw + ((tap + 1) & 1) * 8192 + t * 16;
      gload16(src, dst);
      gload16(src + 4096, dst + 4096);
    }

    STAGE(tap, 0);
    if (tap + 1 < KK) ISSUE(tap + 1, 0);
    STAGE(tap, 1);
    if (tap + 1 < KK) ISSUE(tap + 1, 1);
    STAGE(tap, 2);
    if (tap + 1 < KK) ISSUE(tap + 1, 2);
    STAGE(tap, 3);
    if (tap + 1 < KK) ISSUE(tap + 1, 3);

    // --- 32x32x16 MFMA: B col=l&31 (px), k=(l>>5)*8+e; A row=l&31 (o), same k ---
    const char* wl = smw + (tap & 1) * 8192;
    __builtin_amdgcn_s_setprio(1);
#pragma unroll
    for (int ks = 0; ks < 4; ++ks) {
      const f16x8 bf = *(const f16x8*)(smb + rdb + ((((ks << 1) + (l >> 5)) ^ (l & 7)) << 4));
      const f16x8 a0 = *(const f16x8*)(wl + (((ks * 2 + 0) * 64 + l) << 4));
      acc[0] = __builtin_amdgcn_mfma_f32_32x32x16_f16(a0, bf, acc[0], 0, 0, 0);
      const f16x8 a1 = *(const f16x8*)(wl + (((ks * 2 + 1) * 64 + l) << 4));
      acc[1] = __builtin_amdgcn_mfma_f32_32x32x16_f16(a1, bf, acc[1], 0, 0, 0);
    }
    __builtin_amdgcn_s_setprio(0);
  }
#undef ISSUE
#undef LERPH
#undef STAGE

  // --- epilogue: C/D 32x32 map: col=l&31 -> px, row=(r&3)+8*(r>>2)+4*(l>>5) -> o ---
#pragma unroll
  for (int mt = 0; mt < 2; ++mt)
#pragma unroll
    for (int r = 0; r < 16; ++r) {
      const int o = mt * 32 + (r & 3) + 8 * (r >> 2) + 4 * (l >> 5);
      out[((size_t)(b * O + o) * H + h) * W + wbase + (l & 31)] = acc[mt][r];
    }
}

// ---------- fallback (round-1 kernel, used only if ws too small) ----------
namespace fb {
constexpr int WT = 32, CH = 16, NCHUNK = 4, KC = 144, WPAD = 68;
}
__global__ __launch_bounds__(PREPT, 2)
void deform_conv_fused(const float* __restrict__ x, const float* __restrict__ offs,
                       const float* __restrict__ wgt, float* __restrict__ out) {
  using namespace fb;
  __shared__ int   s_i0[KK][WT];
  __shared__ int   s_j0[KK][WT];
  __shared__ float s_fi[KK][WT];
  __shared__ float s_fj[KK][WT];
  __shared__ float s_w[KC][WPAD];
  __shared__ float s_m[KC][WT + 1];
  const int t = threadIdx.x;
  const int nwt = W / WT;
  const int wt = blockIdx.x % nwt, h = (blockIdx.x / nwt) % H, b = blockIdx.x / (nwt * H);
  const int w0 = wt * WT;
  for (int idx = t; idx < KK * WT; idx += PREPT) {
    const int k = idx / WT, p = idx % WT, w = w0 + p;
    const float oi = offs[(((size_t)b * (2 * KK) + 2 * k) * H + h) * W + w];
    const float oj = offs[(((size_t)b * (2 * KK) + 2 * k + 1) * H + h) * W + w];
    const float ci = oi + (float)(h + (k / 3) - 1), cj = oj + (float)(w + (k % 3) - 1);
    const float fli = floorf(ci), flj = floorf(cj);
    s_i0[k][p] = (int)fli; s_j0[k][p] = (int)flj;
    s_fi[k][p] = ci - fli; s_fj[k][p] = cj - flj;
  }
  float acc[8];
#pragma unroll
  for (int i = 0; i < 8; ++i) acc[i] = 0.f;
  const int p = t & (WT - 1), ob = (t >> 5) * 8;
  for (int cc = 0; cc < NCHUNK; ++cc) {
    const int c0 = cc * CH;
    __syncthreads();
    for (int idx = t; idx < O * KC; idx += PREPT)
      s_w[idx % KC][idx / KC] = wgt[(size_t)(idx / KC) * (C * KK) + (size_t)c0 * KK + idx % KC];
    for (int idx = t; idx < CH * KK * WT; idx += PREPT) {
      const int pp = idx & (WT - 1), rest = idx >> 5, k = rest % KK, cl = rest / KK;
      const int i0 = s_i0[k][pp], j0 = s_j0[k][pp], i1 = i0 + 1, j1 = j0 + 1;
      const float fi = s_fi[k][pp], fj = s_fj[k][pp];
      const float* xb = x + (size_t)(b * C + c0 + cl) * H * W;
      const float v00 = ((unsigned)i0 < (unsigned)H && (unsigned)j0 < (unsigned)W) ? xb[i0 * W + j0] : 0.f;
      const float v01 = ((unsigned)i0 < (unsigned)H && (unsigned)j1 < (unsigned)W) ? xb[i0 * W + j1] : 0.f;
      const float v10 = ((unsigned)i1 < (unsigned)H && (unsigned)j0 < (unsigned)W) ? xb[i1 * W + j0] : 0.f;
      const float v11 = ((unsigned)i1 < (unsigned)H && (unsigned)j1 < (unsigned)W) ? xb[i1 * W + j1] : 0.f;
      const float top = v00 + fj * (v01 - v00), bot = v10 + fj * (v11 - v10);
      s_m[cl * KK + k][pp] = top + fi * (bot - top);
    }
    __syncthreads();
#pragma unroll 4
    for (int k = 0; k < KC; ++k) {
      const float a = s_m[k][p];
      const float4 wv0 = *reinterpret_cast<const float4*>(&s_w[k][ob]);
      const float4 wv1 = *reinterpret_cast<const float4*>(&s_w[k][ob + 4]);
      acc[0] += a * wv0.x; acc[1] += a * wv0.y; acc[2] += a * wv0.z; acc[3] += a * wv0.w;
      acc[4] += a * wv1.x; acc[5] += a * wv1.y; acc[6] += a * wv1.z; acc[7] += a * wv1.w;
    }
  }
#pragma unroll
  for (int i = 0; i < 8; ++i)
    out[(((size_t)b * O + ob + i) * H + h) * W + w0 + p] = acc[i];
}

extern "C" void kernel_launch(void* const* d_in, const int* in_sizes, int n_in,
                              void* d_out, int out_size, void* d_ws, size_t ws_size,
                              hipStream_t stream) {
  const float* x    = (const float*)d_in[0];
  const float* offs = (const float*)d_in[1];
  const float* wgt  = (const float*)d_in[2];
  float* out = (float*)d_out;

  if (ws_size < WS_NEED) {   // fallback: round-1 kernel
    deform_conv_fused<<<B * H * (W / 32), PREPT, 0, stream>>>(x, offs, wgt, out);
    return;
  }
  char* xt = (char*)d_ws;
  unsigned short* wf = (unsigned short*)(xt + XT_BYTES);

  prep_fused<<<B * H * 2, PREPT, 0, stream>>>(x, wgt, (unsigned*)xt, wf);
  deform_mfma<<<B * H, MAINT, 0, stream>>>(offs, xt, (const char*)wf, out);
}

// Round 17
// 27.588 us; speedup vs baseline: 1.1641x; 1.1641x over previous
//
#include <hip/hip_runtime.h>

namespace {
constexpr int B = 4, C = 64, H = 128, W = 128, O = 64, KK = 9;
constexpr int PREPT = 256;
constexpr int WF_ELEMS = KK * 2 * 4 * 64 * 8;                   // 36864
constexpr int WF_BYTES_I = WF_ELEMS * 2;                        // 73728 (8KB/tap)
constexpr size_t XT_BYTES = (size_t)B * H * W * C * 2;
constexpr size_t WS_NEED  = XT_BYTES + (size_t)WF_BYTES_I;
constexpr int DYN_LDS = WF_BYTES_I + 32768 + 18432 + 9216;      // 134144
}

typedef float    f32x4 __attribute__((ext_vector_type(4)));
typedef _Float16 f16x2 __attribute__((ext_vector_type(2)));
typedef _Float16 f16x8 __attribute__((ext_vector_type(8)));

__device__ __forceinline__ unsigned hpack2(float a, float b) {  // 2x f32 -> packed f16
  f16x2 v; v[0] = (_Float16)a; v[1] = (_Float16)b;
  return __builtin_bit_cast(unsigned, v);
}
__device__ __forceinline__ void gload16(const void* g, void* l) {
  __builtin_amdgcn_global_load_lds(
      (const __attribute__((address_space(1))) unsigned*)g,
      (__attribute__((address_space(3))) unsigned*)l, 16, 0, 0);
}

// ---------- prep: x -> x_t[b][h][w][c] f16,  + weight->f16 frag (16x16 order) ----------
__global__ __launch_bounds__(PREPT)
void prep_fused(const float* __restrict__ x, const float* __restrict__ wgt,
                unsigned* __restrict__ xt_u32, unsigned short* __restrict__ wf) {
  __shared__ float st[64][65];
  const int t = threadIdx.x;

  // o = mt*16 + (lane&15), c = ks*32 + (lane>>4)*8 + e
  const int gid = blockIdx.x * PREPT + t;
  if (gid < WF_ELEMS) {
    const int e = gid & 7, lane = (gid >> 3) & 63, mt = (gid >> 9) & 3;
    const int ks = (gid >> 11) & 1, tap = gid >> 12;
    const int o = mt * 16 + (lane & 15);
    const int c = ks * 32 + ((lane >> 4) << 3) + e;
    const _Float16 hv = (_Float16)wgt[(size_t)o * (C * KK) + c * KK + tap];
    wf[gid] = __builtin_bit_cast(unsigned short, hv);
  }

  const int half = blockIdx.x & 1, h = (blockIdx.x >> 1) & 127, b = blockIdx.x >> 8;
  const int w0 = half * 64;
#pragma unroll
  for (int it = 0; it < 4; ++it) {
    const int w4 = (t & 15) * 4, c = it * 16 + (t >> 4);
    const float4 v = *(const float4*)&x[((size_t)(b * C + c) * H + h) * W + w0 + w4];
    st[w4 + 0][c] = v.x; st[w4 + 1][c] = v.y;
    st[w4 + 2][c] = v.z; st[w4 + 3][c] = v.w;
  }
  __syncthreads();
#pragma unroll
  for (int it = 0; it < 8; ++it) {
    const int idx = it * PREPT + t;
    const int w = idx >> 5, c2 = (idx & 31) * 2;
    xt_u32[(size_t)(((b * H + h) * W) + w0 + w) * 32 + (c2 >> 1)] = hpack2(st[w][c2], st[w][c2 + 1]);
  }
}

// ================== shared macro bodies for both main variants ==================
#define PARAMS_BODY(NW, SPW, SPP)                                              \
  _Pragma("unroll")                                                            \
  for (int it = 0; it < 3; ++it) {                                             \
    const int item = it * 64 + l;                                              \
    if (item < KK * 16) {                                                      \
      const int tap = item >> 4, pix = item & 15;                              \
      const int ki = tap / 3, kj = tap - ki * 3;                               \
      const int w = wbase + pix;                                               \
      const float* ob = offs + ((size_t)b * (2 * KK) + 2 * tap) * (H * W) + h * W + w; \
      const float oi = ob[0], oj = ob[H * W];                                  \
      const float ci = oi + (float)(h + ki - 1);                               \
      const float cj = oj + (float)(w + kj - 1);                               \
      const float fli = floorf(ci), flj = floorf(cj);                          \
      const int i0 = (int)fli, j0 = (int)flj, i1 = i0 + 1, j1 = j0 + 1;        \
      const float fi = ci - fli, fj = cj - flj, gi = 1.f - fi, gj = 1.f - fj;  \
      const bool bi0 = (unsigned)i0 < (unsigned)H, bi1 = (unsigned)i1 < (unsigned)H; \
      const bool bj0 = (unsigned)j0 < (unsigned)W, bj1 = (unsigned)j1 < (unsigned)W; \
      const int ic0 = min(max(i0, 0), H - 1), ic1 = min(max(i1, 0), H - 1);    \
      const int jc0 = min(max(j0, 0), W - 1), jc1 = min(max(j1, 0), W - 1);    \
      const float w00 = gi * gj * (float)(bi0 && bj0);                         \
      const float w01 = gi * fj * (float)(bi0 && bj1);                         \
      const float w10 = fi * gj * (float)(bi1 && bj0);                         \
      const float w11 = fi * fj * (float)(bi1 && bj1);                         \
      SPW(tap, pix, 0) = hpack2(w00, w01);                                     \
      SPW(tap, pix, 1) = hpack2(w10, w11);                                     \
      SPP(tap, pix) = (unsigned)jc0 | ((unsigned)ic0 << 7) |                   \
                      ((unsigned)jc1 << 14) | ((unsigned)ic1 << 21);           \
    }                                                                          \
  }

#define ISSUE_BODY(SPP, TAPX, HS) do {                                         \
    const unsigned v_ = SPP(TAPX, (HS) * 8 + pix8);                            \
    const unsigned i0s = v_ & 0x3F80u;                                         \
    const unsigned j0_ = v_ & 0x7Fu;                                           \
    const unsigned j1_ = (v_ >> 14) & 0x7Fu;                                   \
    const unsigned i1s = (v_ >> 14) & 0x3F80u;                                 \
    g[HS][0] = *(const uint4*)(xb + ((size_t)(i0s | j0_) << 7));               \
    g[HS][1] = *(const uint4*)(xb + ((size_t)(i0s | j1_) << 7));               \
    g[HS][2] = *(const uint4*)(xb + ((size_t)(i1s | j0_) << 7));               \
    g[HS][3] = *(const uint4*)(xb + ((size_t)(i1s | j1_) << 7));               \
  } while (0)

#define LERPH(c0_, c1_, c2_, c3_) __builtin_bit_cast(unsigned, (f16x2)(        \
    __builtin_bit_cast(f16x2, c0_) * W00 + __builtin_bit_cast(f16x2, c1_) * W01 + \
    __builtin_bit_cast(f16x2, c2_) * W10 + __builtin_bit_cast(f16x2, c3_) * W11))

#define STAGE_BODY(SPW, TAPV, HS) do {                                         \
    const uint2 pk = *(const uint2*)&SPW(TAPV, (HS) * 8 + pix8, 0);            \
    const f16x2 pa_ = __builtin_bit_cast(f16x2, pk.x);                         \
    const f16x2 pb_ = __builtin_bit_cast(f16x2, pk.y);                         \
    const f16x2 W00 = {pa_[0], pa_[0]}, W01 = {pa_[1], pa_[1]};                \
    const f16x2 W10 = {pb_[0], pb_[0]}, W11 = {pb_[1], pb_[1]};                \
    uint4* gc = g[HS];                                                         \
    uint4 r;                                                                   \
    r.x = LERPH(gc[0].x, gc[1].x, gc[2].x, gc[3].x);                           \
    r.y = LERPH(gc[0].y, gc[1].y, gc[2].y, gc[3].y);                           \
    r.z = LERPH(gc[0].z, gc[1].z, gc[2].z, gc[3].z);                           \
    r.w = LERPH(gc[0].w, gc[1].w, gc[2].w, gc[3].w);                           \
    *(uint4*)(smb + wb + (HS) * 1024) = r;                                     \
  } while (0)

// ---------- main A: all-weights-resident, barrier-free tap loop ----------
__global__ __launch_bounds__(1024) __attribute__((amdgpu_waves_per_eu(4)))
void deform_mfma_res(const float* __restrict__ offs, const char* __restrict__ xt,
                     const char* __restrict__ wfg, float* __restrict__ out) {
  extern __shared__ char dyn[];
  char* wlds = dyn;                                   // 73728: all 9 taps' A-frags
  char* smb  = dyn + WF_BYTES_I;                      // 32768: s_m (wave-private rows)
  unsigned* pwp = (unsigned*)(dyn + WF_BYTES_I + 32768);   // [16][9][16][2]
  unsigned* ppp = (unsigned*)(dyn + WF_BYTES_I + 32768 + 18432); // [16][9][16]

#define SPWr(tap, pix, j) pwp[(((wid * KK + (tap)) * 16 + (pix)) << 1) + (j)]
#define SPPr(tap, pix)    ppp[(wid * KK + (tap)) * 16 + (pix)]

  const int t = threadIdx.x, l = t & 63, wid = t >> 6;          // wid 0..15
  const int nid = (blockIdx.x & 7) * 32 + (blockIdx.x >> 3);    // XCD swizzle (256)
  const int b = nid >> 6, rp = nid & 63;
  const int h = rp * 2 + (wid >> 3);                             // 2 rows per block
  const int wbase = (wid & 7) * 16;                              // wave's first pixel

  // --- load ALL taps' weights into LDS (1024 thr x 16B = 16KB/iter) ---
  for (int off = t * 16; off < WF_BYTES_I; off += 16384)
    gload16(wfg + off, wlds + off);

  // --- sampling params (wave-private; ordered by lgkmcnt within wave) ---
  PARAMS_BODY(16, SPWr, SPPr)

  const int pix8 = l >> 3, oct = l & 7, cb = oct << 4;
  const char* xb = xt + ((size_t)b * H * W << 7) + cb;

  const int wb  = ((wid * 16 + pix8) << 7) + ((oct ^ pix8) << 4);
  const int rr  = wid * 16 + (l & 15);
  const int rd0 = (rr << 7) + ((((l >> 4)    ) ^ (l & 7)) << 4);
  const int rd1 = (rr << 7) + (((4 + (l >> 4)) ^ (l & 7)) << 4);

  f32x4 acc[4];
#pragma unroll
  for (int mt = 0; mt < 4; ++mt) acc[mt] = (f32x4)0.f;

  uint4 g[2][4];
  ISSUE_BODY(SPPr, 0, 0);
  ISSUE_BODY(SPPr, 0, 1);

  __syncthreads();   // the ONLY barrier: weights resident. Tap loop is barrier-free.

#pragma unroll
  for (int tap = 0; tap < KK; ++tap) {
    STAGE_BODY(SPWr, tap, 0);
    if (tap + 1 < KK) ISSUE_BODY(SPPr, tap + 1, 0);
    STAGE_BODY(SPWr, tap, 1);
    if (tap + 1 < KK) ISSUE_BODY(SPPr, tap + 1, 1);

    const char* wl = wlds + tap * 8192;
    const f16x8 b0 = *(const f16x8*)(smb + rd0);
    const f16x8 b1 = *(const f16x8*)(smb + rd1);
    __builtin_amdgcn_s_setprio(1);
#pragma unroll
    for (int mt = 0; mt < 4; ++mt) {
      const f16x8 a0 = *(const f16x8*)(wl + mt * 1024 + l * 16);
      acc[mt] = __builtin_amdgcn_mfma_f32_16x16x32_f16(a0, b0, acc[mt], 0, 0, 0);
    }
#pragma unroll
    for (int mt = 0; mt < 4; ++mt) {
      const f16x8 a1 = *(const f16x8*)(wl + 4096 + mt * 1024 + l * 16);
      acc[mt] = __builtin_amdgcn_mfma_f32_16x16x32_f16(a1, b1, acc[mt], 0, 0, 0);
    }
    __builtin_amdgcn_s_setprio(0);
  }

#pragma unroll
  for (int mt = 0; mt < 4; ++mt)
#pragma unroll
    for (int j = 0; j < 4; ++j) {
      const int o = mt * 16 + ((l >> 4) << 2) + j;
      out[((size_t)(b * O + o) * H + h) * W + wbase + (l & 15)] = acc[mt][j];
    }
#undef SPWr
#undef SPPr
}

// ---------- main B: round-15 static-LDS variant (fallback if big-LDS unavailable) ----------
__global__ __launch_bounds__(512) __attribute__((amdgpu_waves_per_eu(6)))
void deform_mfma_static(const float* __restrict__ offs, const char* __restrict__ xt,
                        const char* __restrict__ wfg, float* __restrict__ out) {
  __shared__ unsigned short s_wf[2][4096];
  __shared__ unsigned short s_m[128 * 64];
  __shared__ unsigned s_pw[8][KK][16][2];
  __shared__ unsigned s_pp[8][KK][16];

#define SPWs(tap, pix, j) s_pw[wid][tap][pix][j]
#define SPPs(tap, pix)    s_pp[wid][tap][pix]

  const int t = threadIdx.x, l = t & 63, wid = t >> 6;
  const int nid = (blockIdx.x & 7) * 64 + (blockIdx.x >> 3);
  const int h = nid & 127, b = nid >> 7;
  const int wbase = wid * 16;

  PARAMS_BODY(8, SPWs, SPPs)

  const int pix8 = l >> 3, oct = l & 7, cb = oct << 4;
  const char* xb = xt + ((size_t)b * H * W << 7) + cb;

  char* smb = (char*)s_m;
  char* smw = (char*)s_wf;
  const int wb  = ((wid * 16 + pix8) << 7) + ((oct ^ pix8) << 4);
  const int rr  = wid * 16 + (l & 15);
  const int rd0 = (rr << 7) + ((((l >> 4)    ) ^ (l & 7)) << 4);
  const int rd1 = (rr << 7) + (((4 + (l >> 4)) ^ (l & 7)) << 4);

  f32x4 acc[4];
#pragma unroll
  for (int mt = 0; mt < 4; ++mt) acc[mt] = (f32x4)0.f;

  uint4 g[2][4];
  gload16(wfg + (size_t)t * 16, smw + t * 16);
  ISSUE_BODY(SPPs, 0, 0);
  ISSUE_BODY(SPPs, 0, 1);

#pragma unroll 1
  for (int tap = 0; tap < KK; ++tap) {
    __syncthreads();
    if (tap + 1 < KK)
      gload16(wfg + (size_t)(tap + 1) * 8192 + t * 16,
              smw + ((tap + 1) & 1) * 8192 + t * 16);

    STAGE_BODY(SPWs, tap, 0);
    if (tap + 1 < KK) ISSUE_BODY(SPPs, tap + 1, 0);
    STAGE_BODY(SPWs, tap, 1);
    if (tap + 1 < KK) ISSUE_BODY(SPPs, tap + 1, 1);

    const char* wl = smw + (tap & 1) * 8192;
    const f16x8 b0 = *(const f16x8*)(smb + rd0);
    const f16x8 b1 = *(const f16x8*)(smb + rd1);
    __builtin_amdgcn_s_setprio(1);
#pragma unroll
    for (int mt = 0; mt < 4; ++mt) {
      const f16x8 a0 = *(const f16x8*)(wl + mt * 1024 + l * 16);
      acc[mt] = __builtin_amdgcn_mfma_f32_16x16x32_f16(a0, b0, acc[mt], 0, 0, 0);
    }
#pragma unroll
    for (int mt = 0; mt < 4; ++mt) {
      const f16x8 a1 = *(const f16x8*)(wl + 4096 + mt * 1024 + l * 16);
      acc[mt] = __builtin_amdgcn_mfma_f32_16x16x32_f16(a1, b1, acc[mt], 0, 0, 0);
    }
    __builtin_amdgcn_s_setprio(0);
  }

#pragma unroll
  for (int mt = 0; mt < 4; ++mt)
#pragma unroll
    for (int j = 0; j < 4; ++j) {
      const int o = mt * 16 + ((l >> 4) << 2) + j;
      out[((size_t)(b * O + o) * H + h) * W + wbase + (l & 15)] = acc[mt][j];
    }
#undef SPWs
#undef SPPs
}

// ---------- fallback (round-1 kernel, used only if ws too small) ----------
namespace fb {
constexpr int WT = 32, CH = 16, NCHUNK = 4, KC = 144, WPAD = 68;
}
__global__ __launch_bounds__(PREPT, 2)
void deform_conv_fused(const float* __restrict__ x, const float* __restrict__ offs,
                       const float* __restrict__ wgt, float* __restrict__ out) {
  using namespace fb;
  __shared__ int   s_i0[KK][WT];
  __shared__ int   s_j0[KK][WT];
  __shared__ float s_fi[KK][WT];
  __shared__ float s_fj[KK][WT];
  __shared__ float s_w[KC][WPAD];
  __shared__ float s_m[KC][WT + 1];
  const int t = threadIdx.x;
  const int nwt = W / WT;
  const int wt = blockIdx.x % nwt, h = (blockIdx.x / nwt) % H, b = blockIdx.x / (nwt * H);
  const int w0 = wt * WT;
  for (int idx = t; idx < KK * WT; idx += PREPT) {
    const int k = idx / WT, p = idx % WT, w = w0 + p;
    const float oi = offs[(((size_t)b * (2 * KK) + 2 * k) * H + h) * W + w];
    const float oj = offs[(((size_t)b * (2 * KK) + 2 * k + 1) * H + h) * W + w];
    const float ci = oi + (float)(h + (k / 3) - 1), cj = oj + (float)(w + (k % 3) - 1);
    const float fli = floorf(ci), flj = floorf(cj);
    s_i0[k][p] = (int)fli; s_j0[k][p] = (int)flj;
    s_fi[k][p] = ci - fli; s_fj[k][p] = cj - flj;
  }
  float acc[8];
#pragma unroll
  for (int i = 0; i < 8; ++i) acc[i] = 0.f;
  const int p = t & (WT - 1), ob = (t >> 5) * 8;
  for (int cc = 0; cc < NCHUNK; ++cc) {
    const int c0 = cc * CH;
    __syncthreads();
    for (int idx = t; idx < O * KC; idx += PREPT)
      s_w[idx % KC][idx / KC] = wgt[(size_t)(idx / KC) * (C * KK) + (size_t)c0 * KK + idx % KC];
    for (int idx = t; idx < CH * KK * WT; idx += PREPT) {
      const int pp = idx & (WT - 1), rest = idx >> 5, k = rest % KK, cl = rest / KK;
      const int i0 = s_i0[k][pp], j0 = s_j0[k][pp], i1 = i0 + 1, j1 = j0 + 1;
      const float fi = s_fi[k][pp], fj = s_fj[k][pp];
      const float* xb = x + (size_t)(b * C + c0 + cl) * H * W;
      const float v00 = ((unsigned)i0 < (unsigned)H && (unsigned)j0 < (unsigned)W) ? xb[i0 * W + j0] : 0.f;
      const float v01 = ((unsigned)i0 < (unsigned)H && (unsigned)j1 < (unsigned)W) ? xb[i0 * W + j1] : 0.f;
      const float v10 = ((unsigned)i1 < (unsigned)H && (unsigned)j0 < (unsigned)W) ? xb[i1 * W + j0] : 0.f;
      const float v11 = ((unsigned)i1 < (unsigned)H && (unsigned)j1 < (unsigned)W) ? xb[i1 * W + j1] : 0.f;
      const float top = v00 + fj * (v01 - v00), bot = v10 + fj * (v11 - v10);
      s_m[cl * KK + k][pp] = top + fi * (bot - top);
    }
    __syncthreads();
#pragma unroll 4
    for (int k = 0; k < KC; ++k) {
      const float a = s_m[k][p];
      const float4 wv0 = *reinterpret_cast<const float4*>(&s_w[k][ob]);
      const float4 wv1 = *reinterpret_cast<const float4*>(&s_w[k][ob + 4]);
      acc[0] += a * wv0.x; acc[1] += a * wv0.y; acc[2] += a * wv0.z; acc[3] += a * wv0.w;
      acc[4] += a * wv1.x; acc[5] += a * wv1.y; acc[6] += a * wv1.z; acc[7] += a * wv1.w;
    }
  }
#pragma unroll
  for (int i = 0; i < 8; ++i)
    out[(((size_t)b * O + ob + i) * H + h) * W + w0 + p] = acc[i];
}

extern "C" void kernel_launch(void* const* d_in, const int* in_sizes, int n_in,
                              void* d_out, int out_size, void* d_ws, size_t ws_size,
                              hipStream_t stream) {
  const float* x    = (const float*)d_in[0];
  const float* offs = (const float*)d_in[1];
  const float* wgt  = (const float*)d_in[2];
  float* out = (float*)d_out;

  if (ws_size < WS_NEED) {   // fallback: round-1 kernel
    deform_conv_fused<<<B * H * (W / 32), PREPT, 0, stream>>>(x, offs, wgt, out);
    return;
  }
  char* xt = (char*)d_ws;
  unsigned short* wf = (unsigned short*)(xt + XT_BYTES);

  prep_fused<<<B * H * 2, PREPT, 0, stream>>>(x, wgt, (unsigned*)xt, wf);

  hipError_t e = hipFuncSetAttribute((const void*)deform_mfma_res,
                                     hipFuncAttributeMaxDynamicSharedMemorySize,
                                     DYN_LDS);
  if (e == hipSuccess)
    deform_mfma_res<<<B * H / 2, 1024, DYN_LDS, stream>>>(offs, xt, (const char*)wf, out);
  else
    deform_mfma_static<<<B * H, 512, 0, stream>>>(offs, xt, (const char*)wf, out);
}